// Round 8
// baseline (990.893 us; speedup 1.0000x reference)
//
#include <hip/hip_runtime.h>
#include <hip/hip_bf16.h>

typedef __attribute__((ext_vector_type(8))) short bf16x8;
typedef __attribute__((ext_vector_type(4))) float f32x4;

static constexpr int    MROWS = 53248;            // 4096 * 13
static constexpr size_t M64   = (size_t)MROWS * 64;

// ---------------------------------------------------------------- prep: W^T
// W (f32, [2][K][N]) -> Wt (bf16, [2][N][K]); MFMA operands want K contiguous.
__global__ void transpose_w(const float* __restrict__ W, __hip_bfloat16* __restrict__ Wt,
                            int K, int N) {
  int total = 2 * K * N;
  int idx = blockIdx.x * 256 + threadIdx.x;
  if (idx >= total) return;
  int t   = idx / (K * N);
  int rem = idx - t * K * N;
  int n   = rem / K;
  int k   = rem - n * K;
  Wt[idx] = __float2bfloat16(W[(size_t)t * K * N + (size_t)k * N + n]);
}

// ---------------------------------------------------------------- prep: BN fold
// y = relu(h+b)*s + o with s = g*rsqrt(v+eps), o = be - m*s
__global__ void bn_prep(const float* __restrict__ g, const float* __restrict__ be,
                        const float* __restrict__ m, const float* __restrict__ v,
                        float* __restrict__ s, float* __restrict__ o, int n) {
  int i = blockIdx.x * 256 + threadIdx.x;
  if (i < n) {
    float sc = g[i] * rsqrtf(v[i] + 1e-3f);
    s[i] = sc;
    o[i] = be[i] - m[i] * sc;
  }
}

// ---------------------------------------------------------------- input norm
// x[t][b*13+s][c] = V_{ue}[b, c%32, s, t] * rsqrt(sum_{tx,ri} V^2) , ue = c/32
__global__ __launch_bounds__(256) void input_norm(const float* __restrict__ V1,
                                                  const float* __restrict__ V2,
                                                  __hip_bfloat16* __restrict__ x) {
  __shared__ float lv[1664];   // [ue][tx][s][ri] : 2 * 32*13*2
  __shared__ float inv_s[26];  // [ue][s]
  const int b = blockIdx.x, tid = threadIdx.x;
  for (int idx = tid; idx < 1664; idx += 256)
    lv[idx] = (idx < 832) ? V1[(size_t)b * 832 + idx] : V2[(size_t)b * 832 + idx - 832];
  __syncthreads();
  if (tid < 26) {
    int ue = tid / 13, s = tid - ue * 13;
    const float* base = &lv[ue * 832 + s * 2];
    float sum = 0.f;
#pragma unroll
    for (int tx = 0; tx < 32; ++tx) {
      float a = base[tx * 26], c = base[tx * 26 + 1];
      sum += a * a + c * c;
    }
    inv_s[tid] = rsqrtf(sum);
  }
  __syncthreads();
  for (int idx = tid; idx < 1664; idx += 256) {
    int t = idx / 832, rem = idx - t * 832;
    int s = rem >> 6, c = rem & 63;
    int ue = c >> 5, tx = c & 31;
    float val = lv[ue * 832 + tx * 26 + s * 2 + t] * inv_s[ue * 13 + s];
    x[(size_t)t * M64 + (size_t)(b * 13 + s) * 64 + c] = __float2bfloat16(val);
  }
}

// ---------------------------------------------------------------- direct-from-cache GEMM + fused epilogue
// No LDS, no barriers: A/B fragments loaded straight global->VGPR (16B/lane).
// Weights are L2-resident (<=2MB/tower); A panels are L3-resident (segmented).
// A: bf16, tower stride strideA elems, row offset aRow0.  Wt: bf16 [2][N][K].
// ACT=1: Y = bf16( relu(acc+b)*s + o ).  ACT=0: Z = f32( acc+b ).
template <int N, int K, int BN, int ACT>
__global__ __launch_bounds__(256) void gemm_direct(const __hip_bfloat16* __restrict__ A,
                                                   size_t strideA, int aRow0,
                                                   const __hip_bfloat16* __restrict__ Wt,
                                                   const float* __restrict__ bias,
                                                   const float* __restrict__ sc,
                                                   const float* __restrict__ ofs,
                                                   __hip_bfloat16* __restrict__ Y,
                                                   float* __restrict__ Z,
                                                   size_t strideO, int nby) {
  constexpr int GX = N / BN;        // N-tiles
  constexpr int MI = 4, NI = BN / 32;

  // T1: bijective XCD-chunked swizzle (m204). HW: launch-id L -> XCD L%8.
  // Map so each XCD owns a contiguous chunk of logical tile ids; bx innermost
  // => A-panel siblings + B-reuse neighbors co-located on one XCD's L2.
  const int nwg = GX * nby * 2;
  const int L   = blockIdx.x;
  const int q = nwg >> 3, r = nwg & 7;
  const int xcd = L & 7, idx = L >> 3;
  const int wg = (xcd < r ? xcd * (q + 1) : r * (q + 1) + (xcd - r) * q) + idx;
  const int t   = wg / (GX * nby);
  const int rem = wg - t * (GX * nby);
  const int by  = rem / GX;
  const int bx  = rem - by * GX;
  const int m0 = by * 128, n0 = bx * BN;

  const int lane = threadIdx.x & 63, wave = threadIdx.x >> 6;
  const int wr = wave >> 1, wc = wave & 1;
  const int l15 = lane & 15, lhi = lane >> 4;

  const __hip_bfloat16* Ab = A + (size_t)t * strideA + (size_t)(aRow0 + m0) * K;
  const __hip_bfloat16* Wb = Wt + (size_t)t * N * K + (size_t)n0 * K;

  f32x4 acc[MI][NI];
#pragma unroll
  for (int i = 0; i < MI; ++i)
#pragma unroll
    for (int j = 0; j < NI; ++j) acc[i][j] = (f32x4){0.f, 0.f, 0.f, 0.f};

#pragma unroll 2
  for (int k0 = 0; k0 < K; k0 += 64) {
#pragma unroll
    for (int kk = 0; kk < 2; ++kk) {
      const int ko = k0 + kk * 32 + lhi * 8;
      bf16x8 af[MI], bfr[NI];
#pragma unroll
      for (int i = 0; i < MI; ++i)
        af[i] = *(const bf16x8*)&Ab[(size_t)(wr * 64 + i * 16 + l15) * K + ko];
#pragma unroll
      for (int j = 0; j < NI; ++j)
        bfr[j] = *(const bf16x8*)&Wb[(size_t)(wc * (BN / 2) + j * 16 + l15) * K + ko];
#pragma unroll
      for (int i = 0; i < MI; ++i)
#pragma unroll
        for (int j = 0; j < NI; ++j)
          acc[i][j] = __builtin_amdgcn_mfma_f32_16x16x32_bf16(af[i], bfr[j], acc[i][j], 0, 0, 0);
    }
  }

  // ---- epilogue (C/D: row=(lane>>4)*4+r, col=lane&15)
  const int gcb = n0 + wc * (BN / 2) + l15;
  float bi[NI], si[NI], oi[NI];
#pragma unroll
  for (int j = 0; j < NI; ++j) {
    int gc = gcb + j * 16;
    bi[j] = bias[t * N + gc];
    if constexpr (ACT) {
      si[j] = sc[t * N + gc];
      oi[j] = ofs[t * N + gc];
    }
  }
#pragma unroll
  for (int i = 0; i < MI; ++i) {
    int grow = m0 + wr * 64 + i * 16 + lhi * 4;
#pragma unroll
    for (int j = 0; j < NI; ++j) {
      int gc = gcb + j * 16;
#pragma unroll
      for (int rr = 0; rr < 4; ++rr) {
        float val = acc[i][j][rr] + bi[j];
        if constexpr (ACT) {
          val = fmaxf(val, 0.f) * si[j] + oi[j];
          Y[(size_t)t * strideO + (size_t)(grow + rr) * N + gc] = __float2bfloat16(val);
        } else {
          Z[(size_t)t * strideO + (size_t)(grow + rr) * N + gc] = val;
        }
      }
    }
  }
}

// ---------------------------------------------------------------- post: sigmoid + joint norm + scatter
// Z: f32 seg-local [2][nr][64] (tower stride zstride), o = tx*2+ue.
// out f32: out[((b*64+ue*32+tx)*13+s)*2+ri], global row = row0 + zrow.
__global__ __launch_bounds__(256) void postproc(const float* __restrict__ Z,
                                                size_t zstride, int row0,
                                                float* __restrict__ out) {
  const int zrow = blockIdx.x * 4 + (threadIdx.x >> 6);
  const int o = threadIdx.x & 63;
  float zr = Z[(size_t)zrow * 64 + o];
  float zl = Z[zstride + (size_t)zrow * 64 + o];
  float vi = 1.f / (1.f + expf(-zl));
  float p = zr * zr + vi * vi;
  p += __shfl_xor(p, 2);
  p += __shfl_xor(p, 4);
  p += __shfl_xor(p, 8);
  p += __shfl_xor(p, 16);
  p += __shfl_xor(p, 32);   // sum over the 32 lanes with same ue parity (= over tx)
  float inv = rsqrtf(p);
  int grow = row0 + zrow;
  int bb = grow / 13, s = grow - bb * 13;
  int tx = o >> 1, ue = o & 1;
  size_t base = (((size_t)bb * 64 + ue * 32 + tx) * 13 + s) * 2;
  out[base]     = zr * inv;
  out[base + 1] = vi * inv;
}

// ---------------------------------------------------------------- launch
extern "C" void kernel_launch(void* const* d_in, const int* in_sizes, int n_in,
                              void* d_out, int out_size, void* d_ws, size_t ws_size,
                              hipStream_t stream) {
  const float* V1 = (const float*)d_in[0];
  const float* V2 = (const float*)d_in[1];
  const float* W1 = (const float*)d_in[2];
  const float* b1 = (const float*)d_in[3];
  const float* g1 = (const float*)d_in[4];
  const float* be1 = (const float*)d_in[5];
  const float* m1 = (const float*)d_in[6];
  const float* v1 = (const float*)d_in[7];
  const float* W2 = (const float*)d_in[8];
  const float* b2 = (const float*)d_in[9];
  const float* g2 = (const float*)d_in[10];
  const float* be2 = (const float*)d_in[11];
  const float* m2 = (const float*)d_in[12];
  const float* v2 = (const float*)d_in[13];
  const float* W3 = (const float*)d_in[14];
  const float* b3 = (const float*)d_in[15];
  const float* g3 = (const float*)d_in[16];
  const float* be3 = (const float*)d_in[17];
  const float* m3 = (const float*)d_in[18];
  const float* v3 = (const float*)d_in[19];
  const float* W4 = (const float*)d_in[20];
  const float* b4 = (const float*)d_in[21];
  float* out = (float*)d_out;   // reference output dtype = float32

  char* ws = (char*)d_ws;
  // ---- fixed region: weights(bf16,T) + folded BN + x
  constexpr size_t OFF_WT1 = 0;                          // [2][1024][64] bf16
  constexpr size_t OFF_WT2 = OFF_WT1 + 262144;           // [2][512][1024] bf16
  constexpr size_t OFF_WT3 = OFF_WT2 + 2097152;          // [2][512][512] bf16
  constexpr size_t OFF_WT4 = OFF_WT3 + 1048576;          // [2][64][512] bf16
  constexpr size_t OFF_S1  = OFF_WT4 + 131072;           // f32 [2][1024]
  constexpr size_t OFF_O1  = OFF_S1 + 8192;
  constexpr size_t OFF_S2  = OFF_O1 + 8192;              // f32 [2][512]
  constexpr size_t OFF_O2  = OFF_S2 + 4096;
  constexpr size_t OFF_S3  = OFF_O2 + 4096;
  constexpr size_t OFF_O3  = OFF_S3 + 4096;
  constexpr size_t OFF_X   = OFF_O3 + 4096;              // bf16 [2][M][64]  (13.6 MB)
  constexpr size_t FIXED_END = OFF_X + 13631488;         // = 17,203,200 B

  __hip_bfloat16* wt1 = (__hip_bfloat16*)(ws + OFF_WT1);
  __hip_bfloat16* wt2 = (__hip_bfloat16*)(ws + OFF_WT2);
  __hip_bfloat16* wt3 = (__hip_bfloat16*)(ws + OFF_WT3);
  __hip_bfloat16* wt4 = (__hip_bfloat16*)(ws + OFF_WT4);
  float* s1 = (float*)(ws + OFF_S1);
  float* o1 = (float*)(ws + OFF_O1);
  float* s2 = (float*)(ws + OFF_S2);
  float* o2 = (float*)(ws + OFF_O2);
  float* s3 = (float*)(ws + OFF_S3);
  float* o3 = (float*)(ws + OFF_O3);
  __hip_bfloat16* xb = (__hip_bfloat16*)(ws + OFF_X);

  // ---- segment region, sized to fit ws_size (adaptive; deterministic per call).
  // per 128-row block: h1 4096B/row, h2/h3 2048B/row, z 512B/row  => 8704 B/row.
  constexpr int TOT_BLOCKS = 416;  // 53248 / 128
  size_t avail = (ws_size > FIXED_END) ? (ws_size - FIXED_END) : 0;
  long sb = (long)(avail / ((size_t)8704 * 128));
  int seg_blocks = (sb < 1) ? 1 : (sb > TOT_BLOCKS ? TOT_BLOCKS : (int)sb);
  const int seg_rows = seg_blocks * 128;
  const size_t H1E = (size_t)seg_rows * 1024;            // elems per tower
  const size_t H2E = (size_t)seg_rows * 512;
  const size_t ZE  = (size_t)seg_rows * 64;
  const size_t OFF_H1 = FIXED_END;
  const size_t OFF_H2 = OFF_H1 + 2 * H1E * 2;
  const size_t OFF_H3 = OFF_H2 + 2 * H2E * 2;
  const size_t OFF_Z  = OFF_H3 + 2 * H2E * 2;
  __hip_bfloat16* h1 = (__hip_bfloat16*)(ws + OFF_H1);
  __hip_bfloat16* h2 = (__hip_bfloat16*)(ws + OFF_H2);
  __hip_bfloat16* h3 = (__hip_bfloat16*)(ws + OFF_H3);
  float*          zb = (float*)(ws + OFF_Z);

  // ---- weight transposes + BN folds (tiny)
  transpose_w<<<(2 * 64 * 1024 + 255) / 256, 256, 0, stream>>>(W1, wt1, 64, 1024);
  transpose_w<<<(2 * 1024 * 512 + 255) / 256, 256, 0, stream>>>(W2, wt2, 1024, 512);
  transpose_w<<<(2 * 512 * 512 + 255) / 256, 256, 0, stream>>>(W3, wt3, 512, 512);
  transpose_w<<<(2 * 512 * 64 + 255) / 256, 256, 0, stream>>>(W4, wt4, 512, 64);
  bn_prep<<<8, 256, 0, stream>>>(g1, be1, m1, v1, s1, o1, 2048);
  bn_prep<<<4, 256, 0, stream>>>(g2, be2, m2, v2, s2, o2, 1024);
  bn_prep<<<4, 256, 0, stream>>>(g3, be3, m3, v3, s3, o3, 1024);

  input_norm<<<4096, 256, 0, stream>>>(V1, V2, xb);

  // ---- segmented 4-layer pipeline (direct-from-cache GEMMs, no LDS/barriers)
  for (int bl0 = 0; bl0 < TOT_BLOCKS; bl0 += seg_blocks) {
    int nb = (TOT_BLOCKS - bl0 < seg_blocks) ? (TOT_BLOCKS - bl0) : seg_blocks;
    int r0 = bl0 * 128;
    gemm_direct<1024, 64, 128, 1><<<8 * nb * 2, 256, 0, stream>>>(
        xb, M64, r0, wt1, b1, s1, o1, h1, nullptr, H1E, nb);
    gemm_direct<512, 1024, 128, 1><<<4 * nb * 2, 256, 0, stream>>>(
        h1, H1E, 0, wt2, b2, s2, o2, h2, nullptr, H2E, nb);
    gemm_direct<512, 512, 128, 1><<<4 * nb * 2, 256, 0, stream>>>(
        h2, H2E, 0, wt3, b3, s3, o3, h3, nullptr, H2E, nb);
    gemm_direct<64, 512, 64, 0><<<1 * nb * 2, 256, 0, stream>>>(
        h3, H2E, 0, wt4, b4, nullptr, nullptr, nullptr, zb, ZE, nb);
    postproc<<<nb * 32, 256, 0, stream>>>(zb, ZE, r0, out);
  }

  (void)in_sizes; (void)n_in; (void)out_size;
}

// Round 9
// 564.780 us; speedup vs baseline: 1.7545x; 1.7545x over previous
//
#include <hip/hip_runtime.h>
#include <hip/hip_bf16.h>

typedef __attribute__((ext_vector_type(8))) short bf16x8;
typedef __attribute__((ext_vector_type(4))) float f32x4;

#define GLOAD16(gsrc, ldst)                                                    \
  __builtin_amdgcn_global_load_lds(                                            \
      (const __attribute__((address_space(1))) unsigned int*)(const void*)(gsrc), \
      (__attribute__((address_space(3))) unsigned int*)(void*)(ldst), 16, 0, 0)

static constexpr int    MROWS = 53248;            // 4096 * 13
static constexpr size_t M64   = (size_t)MROWS * 64;

// ---------------------------------------------------------------- prep: W^T
__global__ void transpose_w(const float* __restrict__ W, __hip_bfloat16* __restrict__ Wt,
                            int K, int N) {
  int total = 2 * K * N;
  int idx = blockIdx.x * 256 + threadIdx.x;
  if (idx >= total) return;
  int t   = idx / (K * N);
  int rem = idx - t * K * N;
  int n   = rem / K;
  int k   = rem - n * K;
  Wt[idx] = __float2bfloat16(W[(size_t)t * K * N + (size_t)k * N + n]);
}

// ---------------------------------------------------------------- prep: BN fold
__global__ void bn_prep(const float* __restrict__ g, const float* __restrict__ be,
                        const float* __restrict__ m, const float* __restrict__ v,
                        float* __restrict__ s, float* __restrict__ o, int n) {
  int i = blockIdx.x * 256 + threadIdx.x;
  if (i < n) {
    float sc = g[i] * rsqrtf(v[i] + 1e-3f);
    s[i] = sc;
    o[i] = be[i] - m[i] * sc;
  }
}

// ---------------------------------------------------------------- input norm
__global__ __launch_bounds__(256) void input_norm(const float* __restrict__ V1,
                                                  const float* __restrict__ V2,
                                                  __hip_bfloat16* __restrict__ x) {
  __shared__ float lv[1664];   // [ue][tx][s][ri]
  __shared__ float inv_s[26];  // [ue][s]
  const int b = blockIdx.x, tid = threadIdx.x;
  for (int idx = tid; idx < 1664; idx += 256)
    lv[idx] = (idx < 832) ? V1[(size_t)b * 832 + idx] : V2[(size_t)b * 832 + idx - 832];
  __syncthreads();
  if (tid < 26) {
    int ue = tid / 13, s = tid - ue * 13;
    const float* base = &lv[ue * 832 + s * 2];
    float sum = 0.f;
#pragma unroll
    for (int tx = 0; tx < 32; ++tx) {
      float a = base[tx * 26], c = base[tx * 26 + 1];
      sum += a * a + c * c;
    }
    inv_s[tid] = rsqrtf(sum);
  }
  __syncthreads();
  for (int idx = tid; idx < 1664; idx += 256) {
    int t = idx / 832, rem = idx - t * 832;
    int s = rem >> 6, c = rem & 63;
    int ue = c >> 5, tx = c & 31;
    float val = lv[ue * 832 + tx * 26 + s * 2 + t] * inv_s[ue * 13 + s];
    x[(size_t)t * M64 + (size_t)(b * 13 + s) * 64 + c] = __float2bfloat16(val);
  }
}

// ---------------------------------------------------------------- GEMM: m97-structure + T1 swizzle + T3-min dbuf
// A: bf16, tower stride strideA, row offset aRow0.  Wt: bf16 [2][N][K].
// ACT=1: Y = bf16( relu(acc+b)*s + o ).  ACT=0: Z = f32( acc+b ).
template <int N, int K, int BN, int ACT>
__global__ __launch_bounds__(256) void gemm_db(const __hip_bfloat16* __restrict__ A,
                                               size_t strideA, int aRow0,
                                               const __hip_bfloat16* __restrict__ Wt,
                                               const float* __restrict__ bias,
                                               const float* __restrict__ sc,
                                               const float* __restrict__ ofs,
                                               __hip_bfloat16* __restrict__ Y,
                                               float* __restrict__ Z,
                                               size_t strideO, int nby) {
  constexpr int BM = 128, BK = 64;
  constexpr int GX = N / BN;
  constexpr int MI = 4, NI = BN / 32;
  constexpr int AI = (BM * BK) / (256 * 8);
  constexpr int BI = (BN * BK) / (256 * 8);
  constexpr int NT = K / BK;
  __shared__ __align__(16) __hip_bfloat16 lsA[2][BM * BK];
  __shared__ __align__(16) __hip_bfloat16 lsB[2][BN * BK];

  // T1: bijective XCD-chunked swizzle (m204); bx innermost so A-panel siblings
  // and neighboring by-blocks co-locate on one XCD's L2.
  const int nwg = GX * nby * 2;
  const int L   = blockIdx.x;
  const int q = nwg >> 3, r = nwg & 7;
  const int xcd = L & 7, idx = L >> 3;
  const int wg = (xcd < r ? xcd * (q + 1) : r * (q + 1) + (xcd - r) * q) + idx;
  const int t   = wg / (GX * nby);
  const int rem = wg - t * (GX * nby);
  const int by  = rem / GX;
  const int bx  = rem - by * GX;
  const int m0 = by * BM, n0 = bx * BN;

  const int tid = threadIdx.x;
  const int lane = tid & 63, wave = tid >> 6;
  const int wr = wave >> 1, wc = wave & 1;
  const int l15 = lane & 15, lhi = lane >> 4;

  const __hip_bfloat16* Ab = A + (size_t)t * strideA;
  const __hip_bfloat16* Wb = Wt + (size_t)t * N * K;

  f32x4 acc[MI][NI];
#pragma unroll
  for (int i = 0; i < MI; ++i)
#pragma unroll
    for (int j = 0; j < NI; ++j) acc[i][j] = (f32x4){0.f, 0.f, 0.f, 0.f};

  // async stage of one K-tile into LDS buffer `buf` (linear dest; wave-uniform base)
  auto stage = [&](int buf, int k0) {
#pragma unroll
    for (int c = 0; c < AI; ++c) {
      int e = (c * 256 + tid) * 8;
      GLOAD16(&Ab[(size_t)(aRow0 + m0 + (e >> 6)) * K + k0 + (e & 63)],
              &lsA[buf][(c * 256 + wave * 64) * 8]);
    }
#pragma unroll
    for (int c = 0; c < BI; ++c) {
      int e = (c * 256 + tid) * 8;
      GLOAD16(&Wb[(size_t)(n0 + (e >> 6)) * K + k0 + (e & 63)],
              &lsB[buf][(c * 256 + wave * 64) * 8]);
    }
  };

  auto compute = [&](int buf) {
#pragma unroll
    for (int kk = 0; kk < 2; ++kk) {
      bf16x8 af[MI], bfr[NI];
#pragma unroll
      for (int i = 0; i < MI; ++i)
        af[i] = *(const bf16x8*)&lsA[buf][(wr * 64 + i * 16 + l15) * BK + kk * 32 + lhi * 8];
#pragma unroll
      for (int j = 0; j < NI; ++j)
        bfr[j] = *(const bf16x8*)&lsB[buf][(wc * (BN / 2) + j * 16 + l15) * BK + kk * 32 + lhi * 8];
#pragma unroll
      for (int i = 0; i < MI; ++i)
#pragma unroll
        for (int j = 0; j < NI; ++j)
          acc[i][j] = __builtin_amdgcn_mfma_f32_16x16x32_bf16(af[i], bfr[j], acc[i][j], 0, 0, 0);
    }
  };

  // T3-minimum: prologue stage + drain; per-iter {stage next; compute cur; sync}
  stage(0, 0);
  __syncthreads();                 // vmcnt(0)+lgkmcnt(0)+barrier: tile0 resident
  int cur = 0;
  for (int kt = 0; kt < NT - 1; ++kt) {
    stage(cur ^ 1, (kt + 1) * BK);  // issue-early: latency hides under compute
    compute(cur);
    __syncthreads();                // drain next tile + all waves done reading cur
    cur ^= 1;
  }
  compute(cur);                     // last tile (already resident)

  // ---- epilogue (C/D: row=(lane>>4)*4+r, col=lane&15)
  const int gcb = n0 + wc * (BN / 2) + l15;
  float bi[NI], si[NI], oi[NI];
#pragma unroll
  for (int j = 0; j < NI; ++j) {
    int gc = gcb + j * 16;
    bi[j] = bias[t * N + gc];
    if constexpr (ACT) {
      si[j] = sc[t * N + gc];
      oi[j] = ofs[t * N + gc];
    }
  }
#pragma unroll
  for (int i = 0; i < MI; ++i) {
    int grow = m0 + wr * 64 + i * 16 + lhi * 4;
#pragma unroll
    for (int j = 0; j < NI; ++j) {
      int gc = gcb + j * 16;
#pragma unroll
      for (int rr = 0; rr < 4; ++rr) {
        float val = acc[i][j][rr] + bi[j];
        if constexpr (ACT) {
          val = fmaxf(val, 0.f) * si[j] + oi[j];
          Y[(size_t)t * strideO + (size_t)(grow + rr) * N + gc] = __float2bfloat16(val);
        } else {
          Z[(size_t)t * strideO + (size_t)(grow + rr) * N + gc] = val;
        }
      }
    }
  }
}

// ---------------------------------------------------------------- post: sigmoid + joint norm + scatter (f32 out)
__global__ __launch_bounds__(256) void postproc(const float* __restrict__ Z,
                                                size_t zstride, int row0,
                                                float* __restrict__ out) {
  const int zrow = blockIdx.x * 4 + (threadIdx.x >> 6);
  const int o = threadIdx.x & 63;
  float zr = Z[(size_t)zrow * 64 + o];
  float zl = Z[zstride + (size_t)zrow * 64 + o];
  float vi = 1.f / (1.f + expf(-zl));
  float p = zr * zr + vi * vi;
  p += __shfl_xor(p, 2);
  p += __shfl_xor(p, 4);
  p += __shfl_xor(p, 8);
  p += __shfl_xor(p, 16);
  p += __shfl_xor(p, 32);
  float inv = rsqrtf(p);
  int grow = row0 + zrow;
  int bb = grow / 13, s = grow - bb * 13;
  int tx = o >> 1, ue = o & 1;
  size_t base = (((size_t)bb * 64 + ue * 32 + tx) * 13 + s) * 2;
  out[base]     = zr * inv;
  out[base + 1] = vi * inv;
}

// ---------------------------------------------------------------- launch
extern "C" void kernel_launch(void* const* d_in, const int* in_sizes, int n_in,
                              void* d_out, int out_size, void* d_ws, size_t ws_size,
                              hipStream_t stream) {
  const float* V1 = (const float*)d_in[0];
  const float* V2 = (const float*)d_in[1];
  const float* W1 = (const float*)d_in[2];
  const float* b1 = (const float*)d_in[3];
  const float* g1 = (const float*)d_in[4];
  const float* be1 = (const float*)d_in[5];
  const float* m1 = (const float*)d_in[6];
  const float* v1 = (const float*)d_in[7];
  const float* W2 = (const float*)d_in[8];
  const float* b2 = (const float*)d_in[9];
  const float* g2 = (const float*)d_in[10];
  const float* be2 = (const float*)d_in[11];
  const float* m2 = (const float*)d_in[12];
  const float* v2 = (const float*)d_in[13];
  const float* W3 = (const float*)d_in[14];
  const float* b3 = (const float*)d_in[15];
  const float* g3 = (const float*)d_in[16];
  const float* be3 = (const float*)d_in[17];
  const float* m3 = (const float*)d_in[18];
  const float* v3 = (const float*)d_in[19];
  const float* W4 = (const float*)d_in[20];
  const float* b4 = (const float*)d_in[21];
  float* out = (float*)d_out;   // reference output dtype = float32

  char* ws = (char*)d_ws;
  constexpr size_t OFF_WT1 = 0;                          // [2][1024][64] bf16
  constexpr size_t OFF_WT2 = OFF_WT1 + 262144;           // [2][512][1024] bf16
  constexpr size_t OFF_WT3 = OFF_WT2 + 2097152;          // [2][512][512] bf16
  constexpr size_t OFF_WT4 = OFF_WT3 + 1048576;          // [2][64][512] bf16
  constexpr size_t OFF_S1  = OFF_WT4 + 131072;
  constexpr size_t OFF_O1  = OFF_S1 + 8192;
  constexpr size_t OFF_S2  = OFF_O1 + 8192;
  constexpr size_t OFF_O2  = OFF_S2 + 4096;
  constexpr size_t OFF_S3  = OFF_O2 + 4096;
  constexpr size_t OFF_O3  = OFF_S3 + 4096;
  constexpr size_t OFF_X   = OFF_O3 + 4096;              // bf16 [2][M][64]
  constexpr size_t FIXED_END = OFF_X + 13631488;

  __hip_bfloat16* wt1 = (__hip_bfloat16*)(ws + OFF_WT1);
  __hip_bfloat16* wt2 = (__hip_bfloat16*)(ws + OFF_WT2);
  __hip_bfloat16* wt3 = (__hip_bfloat16*)(ws + OFF_WT3);
  __hip_bfloat16* wt4 = (__hip_bfloat16*)(ws + OFF_WT4);
  float* s1 = (float*)(ws + OFF_S1);
  float* o1 = (float*)(ws + OFF_O1);
  float* s2 = (float*)(ws + OFF_S2);
  float* o2 = (float*)(ws + OFF_O2);
  float* s3 = (float*)(ws + OFF_S3);
  float* o3 = (float*)(ws + OFF_O3);
  __hip_bfloat16* xb = (__hip_bfloat16*)(ws + OFF_X);

  constexpr int TOT_BLOCKS = 416;  // 53248 / 128
  size_t avail = (ws_size > FIXED_END) ? (ws_size - FIXED_END) : 0;
  long sb = (long)(avail / ((size_t)8704 * 128));
  int seg_blocks = (sb < 1) ? 1 : (sb > TOT_BLOCKS ? TOT_BLOCKS : (int)sb);
  const int seg_rows = seg_blocks * 128;
  const size_t H1E = (size_t)seg_rows * 1024;
  const size_t H2E = (size_t)seg_rows * 512;
  const size_t ZE  = (size_t)seg_rows * 64;
  const size_t OFF_H1 = FIXED_END;
  const size_t OFF_H2 = OFF_H1 + 2 * H1E * 2;
  const size_t OFF_H3 = OFF_H2 + 2 * H2E * 2;
  const size_t OFF_Z  = OFF_H3 + 2 * H2E * 2;
  __hip_bfloat16* h1 = (__hip_bfloat16*)(ws + OFF_H1);
  __hip_bfloat16* h2 = (__hip_bfloat16*)(ws + OFF_H2);
  __hip_bfloat16* h3 = (__hip_bfloat16*)(ws + OFF_H3);
  float*          zb = (float*)(ws + OFF_Z);

  transpose_w<<<(2 * 64 * 1024 + 255) / 256, 256, 0, stream>>>(W1, wt1, 64, 1024);
  transpose_w<<<(2 * 1024 * 512 + 255) / 256, 256, 0, stream>>>(W2, wt2, 1024, 512);
  transpose_w<<<(2 * 512 * 512 + 255) / 256, 256, 0, stream>>>(W3, wt3, 512, 512);
  transpose_w<<<(2 * 512 * 64 + 255) / 256, 256, 0, stream>>>(W4, wt4, 512, 64);
  bn_prep<<<8, 256, 0, stream>>>(g1, be1, m1, v1, s1, o1, 2048);
  bn_prep<<<4, 256, 0, stream>>>(g2, be2, m2, v2, s2, o2, 1024);
  bn_prep<<<4, 256, 0, stream>>>(g3, be3, m3, v3, s3, o3, 1024);

  input_norm<<<4096, 256, 0, stream>>>(V1, V2, xb);

  for (int bl0 = 0; bl0 < TOT_BLOCKS; bl0 += seg_blocks) {
    int nb = (TOT_BLOCKS - bl0 < seg_blocks) ? (TOT_BLOCKS - bl0) : seg_blocks;
    int r0 = bl0 * 128;
    gemm_db<1024, 64, 128, 1><<<8 * nb * 2, 256, 0, stream>>>(
        xb, M64, r0, wt1, b1, s1, o1, h1, nullptr, H1E, nb);
    gemm_db<512, 1024, 128, 1><<<4 * nb * 2, 256, 0, stream>>>(
        h1, H1E, 0, wt2, b2, s2, o2, h2, nullptr, H2E, nb);
    gemm_db<512, 512, 128, 1><<<4 * nb * 2, 256, 0, stream>>>(
        h2, H2E, 0, wt3, b3, s3, o3, h3, nullptr, H2E, nb);
    gemm_db<64, 512, 64, 0><<<1 * nb * 2, 256, 0, stream>>>(
        h3, H2E, 0, wt4, b4, nullptr, nullptr, nullptr, zb, ZE, nb);
    postproc<<<nb * 32, 256, 0, stream>>>(zb, ZE, r0, out);
  }

  (void)in_sizes; (void)n_in; (void)out_size;
}

// Round 10
// 454.476 us; speedup vs baseline: 2.1803x; 1.2427x over previous
//
#include <hip/hip_runtime.h>
#include <hip/hip_bf16.h>

typedef __attribute__((ext_vector_type(8))) short bf16x8;
typedef __attribute__((ext_vector_type(4))) float f32x4;

#define GLOAD16(gsrc, ldst)                                                    \
  __builtin_amdgcn_global_load_lds(                                            \
      (const __attribute__((address_space(1))) unsigned int*)(const void*)(gsrc), \
      (__attribute__((address_space(3))) unsigned int*)(void*)(ldst), 16, 0, 0)

static constexpr int    MROWS = 53248;            // 4096 * 13
static constexpr size_t M64   = (size_t)MROWS * 64;

// ---------------------------------------------------------------- prep: W^T
__global__ void transpose_w(const float* __restrict__ W, __hip_bfloat16* __restrict__ Wt,
                            int K, int N) {
  int total = 2 * K * N;
  int idx = blockIdx.x * 256 + threadIdx.x;
  if (idx >= total) return;
  int t   = idx / (K * N);
  int rem = idx - t * K * N;
  int n   = rem / K;
  int k   = rem - n * K;
  Wt[idx] = __float2bfloat16(W[(size_t)t * K * N + (size_t)k * N + n]);
}

// ---------------------------------------------------------------- prep: BN fold
__global__ void bn_prep(const float* __restrict__ g, const float* __restrict__ be,
                        const float* __restrict__ m, const float* __restrict__ v,
                        float* __restrict__ s, float* __restrict__ o, int n) {
  int i = blockIdx.x * 256 + threadIdx.x;
  if (i < n) {
    float sc = g[i] * rsqrtf(v[i] + 1e-3f);
    s[i] = sc;
    o[i] = be[i] - m[i] * sc;
  }
}

// ---------------------------------------------------------------- input norm
__global__ __launch_bounds__(256) void input_norm(const float* __restrict__ V1,
                                                  const float* __restrict__ V2,
                                                  __hip_bfloat16* __restrict__ x) {
  __shared__ float lv[1664];
  __shared__ float inv_s[26];
  const int b = blockIdx.x, tid = threadIdx.x;
  for (int idx = tid; idx < 1664; idx += 256)
    lv[idx] = (idx < 832) ? V1[(size_t)b * 832 + idx] : V2[(size_t)b * 832 + idx - 832];
  __syncthreads();
  if (tid < 26) {
    int ue = tid / 13, s = tid - ue * 13;
    const float* base = &lv[ue * 832 + s * 2];
    float sum = 0.f;
#pragma unroll
    for (int tx = 0; tx < 32; ++tx) {
      float a = base[tx * 26], c = base[tx * 26 + 1];
      sum += a * a + c * c;
    }
    inv_s[tid] = rsqrtf(sum);
  }
  __syncthreads();
  for (int idx = tid; idx < 1664; idx += 256) {
    int t = idx / 832, rem = idx - t * 832;
    int s = rem >> 6, c = rem & 63;
    int ue = c >> 5, tx = c & 31;
    float val = lv[ue * 832 + tx * 26 + s * 2 + t] * inv_s[ue * 13 + s];
    x[(size_t)t * M64 + (size_t)(b * 13 + s) * 64 + c] = __float2bfloat16(val);
  }
}

// T1: bijective XCD-chunked swizzle (m204)
__device__ __forceinline__ int xcd_swz(int L, int nwg) {
  int q = nwg >> 3, r = nwg & 7;
  int xcd = L & 7, idx = L >> 3;
  return (xcd < r ? xcd * (q + 1) : r * (q + 1) + (xcd - r) * q) + idx;
}

// ================================================================ 8-phase 256x256 GEMM (T2+T3+T5)
// A: bf16 [2][rows][K] (tower stride strideA, row offset aRow0).  Wt: bf16 [2][N][K].
// ACT=1: Y = bf16(relu(acc+b)*s + o).  ACT=0 unused here.
template <int N, int K, int ACT>
__global__ __launch_bounds__(512, 2) void gemm_8p(const __hip_bfloat16* __restrict__ A,
                                                  size_t strideA, int aRow0,
                                                  const __hip_bfloat16* __restrict__ Wt,
                                                  const float* __restrict__ bias,
                                                  const float* __restrict__ sc,
                                                  const float* __restrict__ ofs,
                                                  __hip_bfloat16* __restrict__ Y,
                                                  float* __restrict__ Z,
                                                  size_t strideO, int nby) {
  constexpr int BK = 64;
  constexpr int GX = N / 256;       // N-tiles
  constexpr int NT = K / BK;
  // LDS: [buf][A/B][256*64] bf16 = 128 KiB total, T2-swizzled contents.
  __shared__ __align__(16) __hip_bfloat16 lds[2][2][256 * 64];

  const int nwg = GX * nby * 2;
  const int wg = xcd_swz(blockIdx.x, nwg);
  const int t   = wg / (GX * nby);
  const int rem = wg - t * (GX * nby);
  const int by  = rem / GX;
  const int bx  = rem - by * GX;
  const int m0 = by * 256, n0 = bx * 256;

  const int tid = threadIdx.x;
  const int lane = tid & 63, wave = tid >> 6;   // 8 waves: 2M x 4N
  const int wr = wave >> 2, wc = wave & 3;
  const int l15 = lane & 15, lhi = lane >> 4;

  const __hip_bfloat16* Ab = A + (size_t)t * strideA;
  const __hip_bfloat16* Wb = Wt + (size_t)t * N * K;

  f32x4 acc[8][4];
#pragma unroll
  for (int i = 0; i < 8; ++i)
#pragma unroll
    for (int j = 0; j < 4; ++j) acc[i][j] = (f32x4){0.f, 0.f, 0.f, 0.f};

  // stage one 16KB half-tile (h: 0,1 = A rows 0-127/128-255; 2,3 = B same) into buf.
  // Linear LDS dest (wave-uniform base + lane*16); T2 pre-swizzled GLOBAL source
  // col_src = col ^ ((row&7)<<3)  [both-sides rule: read applies the same XOR].
  auto stage_half = [&](int buf, int k0, int h) {
#pragma unroll
    for (int c = 0; c < 2; ++c) {
      int e = (c * 512 + tid) * 8;              // elem in [128][64] half
      int rl = e >> 6;
      int col = (e & 63) ^ ((rl & 7) << 3);     // stays 16B-aligned (XOR bits 3-5)
      const __hip_bfloat16* src =
          (h < 2) ? &Ab[(size_t)(aRow0 + m0 + h * 128 + rl) * K + k0 + col]
                  : &Wb[(size_t)(n0 + (h - 2) * 128 + rl) * K + k0 + col];
      GLOAD16(src, &lds[buf][h >> 1][((h & 1) * 128) * 64 + (c * 512 + wave * 64) * 8]);
    }
  };
  // swizzled fragment reads (row&7 == l15&7 since 16-row groups)
  auto ldA = [&](int buf, int mi, int kk) {
    int ra = wr * 128 + mi * 16 + l15;
    return *(const bf16x8*)&lds[buf][0][ra * 64 + ((kk * 32 + lhi * 8) ^ ((l15 & 7) << 3))];
  };
  auto ldB = [&](int buf, int ni, int kk) {
    int rb = wc * 64 + ni * 16 + l15;
    return *(const bf16x8*)&lds[buf][1][rb * 64 + ((kk * 32 + lhi * 8) ^ ((l15 & 7) << 3))];
  };

  // prologue: stage tile 0, drain, barrier
#pragma unroll
  for (int h = 0; h < 4; ++h) stage_half(0, 0, h);
  asm volatile("s_waitcnt vmcnt(0)" ::: "memory");
  __builtin_amdgcn_s_barrier();

  for (int T = 0; T < NT; ++T) {
    const int cur = T & 1, nxt = cur ^ 1;
    const int k1 = (T + 1) * BK;
    const bool pf = (T + 1 < NT);
    bf16x8 a0[8], b0, b1;

    // ---- phase 0: kk=0, ni 0-1 ; stage halves 0,1 of next tile
#pragma unroll
    for (int mi = 0; mi < 8; ++mi) a0[mi] = ldA(cur, mi, 0);
    b0 = ldB(cur, 0, 0); b1 = ldB(cur, 1, 0);
    if (pf) { stage_half(nxt, k1, 0); stage_half(nxt, k1, 1); }
    __builtin_amdgcn_s_barrier();
    __builtin_amdgcn_s_setprio(1);
#pragma unroll
    for (int mi = 0; mi < 8; ++mi) {
      acc[mi][0] = __builtin_amdgcn_mfma_f32_16x16x32_bf16(a0[mi], b0, acc[mi][0], 0, 0, 0);
      acc[mi][1] = __builtin_amdgcn_mfma_f32_16x16x32_bf16(a0[mi], b1, acc[mi][1], 0, 0, 0);
    }
    __builtin_amdgcn_s_setprio(0);

    // ---- phase 1: kk=0, ni 2-3 ; stage halves 2,3
    b0 = ldB(cur, 2, 0); b1 = ldB(cur, 3, 0);
    if (pf) { stage_half(nxt, k1, 2); stage_half(nxt, k1, 3); }
    __builtin_amdgcn_s_barrier();
    __builtin_amdgcn_s_setprio(1);
#pragma unroll
    for (int mi = 0; mi < 8; ++mi) {
      acc[mi][2] = __builtin_amdgcn_mfma_f32_16x16x32_bf16(a0[mi], b0, acc[mi][2], 0, 0, 0);
      acc[mi][3] = __builtin_amdgcn_mfma_f32_16x16x32_bf16(a0[mi], b1, acc[mi][3], 0, 0, 0);
    }
    __builtin_amdgcn_s_setprio(0);

    // ---- phase 2: kk=1, ni 0-1
#pragma unroll
    for (int mi = 0; mi < 8; ++mi) a0[mi] = ldA(cur, mi, 1);
    b0 = ldB(cur, 0, 1); b1 = ldB(cur, 1, 1);
    __builtin_amdgcn_s_barrier();
    __builtin_amdgcn_s_setprio(1);
#pragma unroll
    for (int mi = 0; mi < 8; ++mi) {
      acc[mi][0] = __builtin_amdgcn_mfma_f32_16x16x32_bf16(a0[mi], b0, acc[mi][0], 0, 0, 0);
      acc[mi][1] = __builtin_amdgcn_mfma_f32_16x16x32_bf16(a0[mi], b1, acc[mi][1], 0, 0, 0);
    }
    __builtin_amdgcn_s_setprio(0);

    // ---- phase 3: kk=1, ni 2-3
    b0 = ldB(cur, 2, 1); b1 = ldB(cur, 3, 1);
    __builtin_amdgcn_s_barrier();
    __builtin_amdgcn_s_setprio(1);
#pragma unroll
    for (int mi = 0; mi < 8; ++mi) {
      acc[mi][2] = __builtin_amdgcn_mfma_f32_16x16x32_bf16(a0[mi], b0, acc[mi][2], 0, 0, 0);
      acc[mi][3] = __builtin_amdgcn_mfma_f32_16x16x32_bf16(a0[mi], b1, acc[mi][3], 0, 0, 0);
    }
    __builtin_amdgcn_s_setprio(0);

    // ---- tile end: drain next-tile stages, protect cur-buffer swap
    asm volatile("s_waitcnt vmcnt(0)" ::: "memory");
    __builtin_amdgcn_s_barrier();
  }

  // ---- epilogue (C/D: row=(lane>>4)*4+r, col=lane&15)
  const int gcb = n0 + wc * 64 + l15;
  float bi[4], si[4], oi[4];
#pragma unroll
  for (int j = 0; j < 4; ++j) {
    int gc = gcb + j * 16;
    bi[j] = bias[t * N + gc];
    si[j] = sc[t * N + gc];
    oi[j] = ofs[t * N + gc];
  }
#pragma unroll
  for (int mi = 0; mi < 8; ++mi) {
    int grow = m0 + wr * 128 + mi * 16 + lhi * 4;
#pragma unroll
    for (int j = 0; j < 4; ++j) {
      int gc = gcb + j * 16;
#pragma unroll
      for (int rr = 0; rr < 4; ++rr) {
        float val = acc[mi][j][rr] + bi[j];
        val = fmaxf(val, 0.f) * si[j] + oi[j];
        Y[(size_t)t * strideO + (size_t)(grow + rr) * N + gc] = __float2bfloat16(val);
      }
    }
  }
  (void)Z;
}

// ================================================================ 128-tile dbuf GEMM (L1/L4) + T2 swizzle
template <int N, int K, int BN, int ACT>
__global__ __launch_bounds__(256) void gemm_db(const __hip_bfloat16* __restrict__ A,
                                               size_t strideA, int aRow0,
                                               const __hip_bfloat16* __restrict__ Wt,
                                               const float* __restrict__ bias,
                                               const float* __restrict__ sc,
                                               const float* __restrict__ ofs,
                                               __hip_bfloat16* __restrict__ Y,
                                               float* __restrict__ Z,
                                               size_t strideO, int nby) {
  constexpr int BM = 128, BK = 64;
  constexpr int GX = N / BN;
  constexpr int MI = 4, NI = BN / 32;
  constexpr int AI = (BM * BK) / (256 * 8);
  constexpr int BI = (BN * BK) / (256 * 8);
  constexpr int NT = K / BK;
  __shared__ __align__(16) __hip_bfloat16 lsA[2][BM * BK];
  __shared__ __align__(16) __hip_bfloat16 lsB[2][BN * BK];

  const int nwg = GX * nby * 2;
  const int wg = xcd_swz(blockIdx.x, nwg);
  const int t   = wg / (GX * nby);
  const int rem = wg - t * (GX * nby);
  const int by  = rem / GX;
  const int bx  = rem - by * GX;
  const int m0 = by * BM, n0 = bx * BN;

  const int tid = threadIdx.x;
  const int lane = tid & 63, wave = tid >> 6;
  const int wr = wave >> 1, wc = wave & 1;
  const int l15 = lane & 15, lhi = lane >> 4;

  const __hip_bfloat16* Ab = A + (size_t)t * strideA;
  const __hip_bfloat16* Wb = Wt + (size_t)t * N * K;

  f32x4 acc[MI][NI];
#pragma unroll
  for (int i = 0; i < MI; ++i)
#pragma unroll
    for (int j = 0; j < NI; ++j) acc[i][j] = (f32x4){0.f, 0.f, 0.f, 0.f};

  auto stage = [&](int buf, int k0) {
#pragma unroll
    for (int c = 0; c < AI; ++c) {
      int e = (c * 256 + tid) * 8;
      int col = (e & 63) ^ (((e >> 6) & 7) << 3);   // T2 pre-swizzled source
      GLOAD16(&Ab[(size_t)(aRow0 + m0 + (e >> 6)) * K + k0 + col],
              &lsA[buf][(c * 256 + wave * 64) * 8]);
    }
#pragma unroll
    for (int c = 0; c < BI; ++c) {
      int e = (c * 256 + tid) * 8;
      int col = (e & 63) ^ (((e >> 6) & 7) << 3);
      GLOAD16(&Wb[(size_t)(n0 + (e >> 6)) * K + k0 + col],
              &lsB[buf][(c * 256 + wave * 64) * 8]);
    }
  };

  auto compute = [&](int buf) {
#pragma unroll
    for (int kk = 0; kk < 2; ++kk) {
      bf16x8 af[MI], bfr[NI];
#pragma unroll
      for (int i = 0; i < MI; ++i)
        af[i] = *(const bf16x8*)&lsA[buf][(wr * 64 + i * 16 + l15) * BK +
                                          ((kk * 32 + lhi * 8) ^ ((l15 & 7) << 3))];
#pragma unroll
      for (int j = 0; j < NI; ++j)
        bfr[j] = *(const bf16x8*)&lsB[buf][(wc * (BN / 2) + j * 16 + l15) * BK +
                                           ((kk * 32 + lhi * 8) ^ ((l15 & 7) << 3))];
#pragma unroll
      for (int i = 0; i < MI; ++i)
#pragma unroll
        for (int j = 0; j < NI; ++j)
          acc[i][j] = __builtin_amdgcn_mfma_f32_16x16x32_bf16(af[i], bfr[j], acc[i][j], 0, 0, 0);
    }
  };

  stage(0, 0);
  __syncthreads();
  int cur = 0;
  for (int kt = 0; kt < NT - 1; ++kt) {
    stage(cur ^ 1, (kt + 1) * BK);
    compute(cur);
    __syncthreads();
    cur ^= 1;
  }
  compute(cur);

  const int gcb = n0 + wc * (BN / 2) + l15;
  float bi[NI], si[NI], oi[NI];
#pragma unroll
  for (int j = 0; j < NI; ++j) {
    int gc = gcb + j * 16;
    bi[j] = bias[t * N + gc];
    if constexpr (ACT) {
      si[j] = sc[t * N + gc];
      oi[j] = ofs[t * N + gc];
    }
  }
#pragma unroll
  for (int i = 0; i < MI; ++i) {
    int grow = m0 + wr * 64 + i * 16 + lhi * 4;
#pragma unroll
    for (int j = 0; j < NI; ++j) {
      int gc = gcb + j * 16;
#pragma unroll
      for (int rr = 0; rr < 4; ++rr) {
        float val = acc[i][j][rr] + bi[j];
        if constexpr (ACT) {
          val = fmaxf(val, 0.f) * si[j] + oi[j];
          Y[(size_t)t * strideO + (size_t)(grow + rr) * N + gc] = __float2bfloat16(val);
        } else {
          Z[(size_t)t * strideO + (size_t)(grow + rr) * N + gc] = val;
        }
      }
    }
  }
}

// ---------------------------------------------------------------- post: sigmoid + joint norm + scatter (f32 out)
__global__ __launch_bounds__(256) void postproc(const float* __restrict__ Z,
                                                size_t zstride, int row0,
                                                float* __restrict__ out) {
  const int zrow = blockIdx.x * 4 + (threadIdx.x >> 6);
  const int o = threadIdx.x & 63;
  float zr = Z[(size_t)zrow * 64 + o];
  float zl = Z[zstride + (size_t)zrow * 64 + o];
  float vi = 1.f / (1.f + expf(-zl));
  float p = zr * zr + vi * vi;
  p += __shfl_xor(p, 2);
  p += __shfl_xor(p, 4);
  p += __shfl_xor(p, 8);
  p += __shfl_xor(p, 16);
  p += __shfl_xor(p, 32);
  float inv = rsqrtf(p);
  int grow = row0 + zrow;
  int bb = grow / 13, s = grow - bb * 13;
  int tx = o >> 1, ue = o & 1;
  size_t base = (((size_t)bb * 64 + ue * 32 + tx) * 13 + s) * 2;
  out[base]     = zr * inv;
  out[base + 1] = vi * inv;
}

// ---------------------------------------------------------------- launch
extern "C" void kernel_launch(void* const* d_in, const int* in_sizes, int n_in,
                              void* d_out, int out_size, void* d_ws, size_t ws_size,
                              hipStream_t stream) {
  const float* V1 = (const float*)d_in[0];
  const float* V2 = (const float*)d_in[1];
  const float* W1 = (const float*)d_in[2];
  const float* b1 = (const float*)d_in[3];
  const float* g1 = (const float*)d_in[4];
  const float* be1 = (const float*)d_in[5];
  const float* m1 = (const float*)d_in[6];
  const float* v1 = (const float*)d_in[7];
  const float* W2 = (const float*)d_in[8];
  const float* b2 = (const float*)d_in[9];
  const float* g2 = (const float*)d_in[10];
  const float* be2 = (const float*)d_in[11];
  const float* m2 = (const float*)d_in[12];
  const float* v2 = (const float*)d_in[13];
  const float* W3 = (const float*)d_in[14];
  const float* b3 = (const float*)d_in[15];
  const float* g3 = (const float*)d_in[16];
  const float* be3 = (const float*)d_in[17];
  const float* m3 = (const float*)d_in[18];
  const float* v3 = (const float*)d_in[19];
  const float* W4 = (const float*)d_in[20];
  const float* b4 = (const float*)d_in[21];
  float* out = (float*)d_out;   // reference output dtype = float32

  char* ws = (char*)d_ws;
  constexpr size_t OFF_WT1 = 0;
  constexpr size_t OFF_WT2 = OFF_WT1 + 262144;
  constexpr size_t OFF_WT3 = OFF_WT2 + 2097152;
  constexpr size_t OFF_WT4 = OFF_WT3 + 1048576;
  constexpr size_t OFF_S1  = OFF_WT4 + 131072;
  constexpr size_t OFF_O1  = OFF_S1 + 8192;
  constexpr size_t OFF_S2  = OFF_O1 + 8192;
  constexpr size_t OFF_O2  = OFF_S2 + 4096;
  constexpr size_t OFF_S3  = OFF_O2 + 4096;
  constexpr size_t OFF_O3  = OFF_S3 + 4096;
  constexpr size_t OFF_X   = OFF_O3 + 4096;
  constexpr size_t FIXED_END = OFF_X + 13631488;

  __hip_bfloat16* wt1 = (__hip_bfloat16*)(ws + OFF_WT1);
  __hip_bfloat16* wt2 = (__hip_bfloat16*)(ws + OFF_WT2);
  __hip_bfloat16* wt3 = (__hip_bfloat16*)(ws + OFF_WT3);
  __hip_bfloat16* wt4 = (__hip_bfloat16*)(ws + OFF_WT4);
  float* s1 = (float*)(ws + OFF_S1);
  float* o1 = (float*)(ws + OFF_O1);
  float* s2 = (float*)(ws + OFF_S2);
  float* o2 = (float*)(ws + OFF_O2);
  float* s3 = (float*)(ws + OFF_S3);
  float* o3 = (float*)(ws + OFF_O3);
  __hip_bfloat16* xb = (__hip_bfloat16*)(ws + OFF_X);

  constexpr int TOT_BLOCKS = 416;  // 53248 / 128
  size_t avail = (ws_size > FIXED_END) ? (ws_size - FIXED_END) : 0;
  long sb = (long)(avail / ((size_t)8704 * 128));
  int seg_blocks = (sb < 2) ? 2 : (sb > TOT_BLOCKS ? TOT_BLOCKS : (int)sb);
  seg_blocks &= ~1;                 // even: 256-row tiles for gemm_8p
  const int seg_rows = seg_blocks * 128;
  const size_t H1E = (size_t)seg_rows * 1024;
  const size_t H2E = (size_t)seg_rows * 512;
  const size_t ZE  = (size_t)seg_rows * 64;
  const size_t OFF_H1 = FIXED_END;
  const size_t OFF_H2 = OFF_H1 + 2 * H1E * 2;
  const size_t OFF_H3 = OFF_H2 + 2 * H2E * 2;
  const size_t OFF_Z  = OFF_H3 + 2 * H2E * 2;
  __hip_bfloat16* h1 = (__hip_bfloat16*)(ws + OFF_H1);
  __hip_bfloat16* h2 = (__hip_bfloat16*)(ws + OFF_H2);
  __hip_bfloat16* h3 = (__hip_bfloat16*)(ws + OFF_H3);
  float*          zb = (float*)(ws + OFF_Z);

  transpose_w<<<(2 * 64 * 1024 + 255) / 256, 256, 0, stream>>>(W1, wt1, 64, 1024);
  transpose_w<<<(2 * 1024 * 512 + 255) / 256, 256, 0, stream>>>(W2, wt2, 1024, 512);
  transpose_w<<<(2 * 512 * 512 + 255) / 256, 256, 0, stream>>>(W3, wt3, 512, 512);
  transpose_w<<<(2 * 512 * 64 + 255) / 256, 256, 0, stream>>>(W4, wt4, 512, 64);
  bn_prep<<<8, 256, 0, stream>>>(g1, be1, m1, v1, s1, o1, 2048);
  bn_prep<<<4, 256, 0, stream>>>(g2, be2, m2, v2, s2, o2, 1024);
  bn_prep<<<4, 256, 0, stream>>>(g3, be3, m3, v3, s3, o3, 1024);

  input_norm<<<4096, 256, 0, stream>>>(V1, V2, xb);

  for (int bl0 = 0; bl0 < TOT_BLOCKS; bl0 += seg_blocks) {
    int nb = (TOT_BLOCKS - bl0 < seg_blocks) ? (TOT_BLOCKS - bl0) : seg_blocks;
    int r0 = bl0 * 128;
    int nby8 = nb / 2;               // 256-row tiles (nb even by construction)
    gemm_db<1024, 64, 128, 1><<<8 * nb * 2, 256, 0, stream>>>(
        xb, M64, r0, wt1, b1, s1, o1, h1, nullptr, H1E, nb);
    gemm_8p<512, 1024, 1><<<2 * nby8 * 2, 512, 0, stream>>>(
        h1, H1E, 0, wt2, b2, s2, o2, h2, nullptr, H2E, nby8);
    gemm_8p<512, 512, 1><<<2 * nby8 * 2, 512, 0, stream>>>(
        h2, H2E, 0, wt3, b3, s3, o3, h3, nullptr, H2E, nby8);
    gemm_db<64, 512, 64, 0><<<1 * nb * 2, 256, 0, stream>>>(
        h3, H2E, 0, wt4, b4, nullptr, nullptr, nullptr, zb, ZE, nb);
    postproc<<<nb * 32, 256, 0, stream>>>(zb, ZE, r0, out);
  }

  (void)in_sizes; (void)n_in; (void)out_size;
}